// Round 5
// baseline (535.009 us; speedup 1.0000x reference)
//
#include <hip/hip_runtime.h>
#include <hip/hip_bf16.h>

// S=2048, E=2048, H=16, D=128
#define S_LEN 2048
#define EMB   2048
#define NH    16
#define HD    128

typedef __bf16 bf16x8 __attribute__((ext_vector_type(8)));
typedef __bf16 bf16x4 __attribute__((ext_vector_type(4)));
typedef float  f32x4  __attribute__((ext_vector_type(4)));
typedef short  s16x4  __attribute__((ext_vector_type(4)));

__device__ __forceinline__ void async_copy16(void* lds, const void* g) {
  __builtin_amdgcn_global_load_lds((__attribute__((address_space(1))) void*)(void*)g,
                                   (__attribute__((address_space(3))) void*)lds, 16, 0, 0);
}

__device__ __forceinline__ unsigned lds_addr(const void* p) {
  return (unsigned)(uintptr_t)(const __attribute__((address_space(3))) char*)p;
}

__device__ __forceinline__ s16x4 tr16(unsigned addr) {
  s16x4 d;
  asm volatile("ds_read_b64_tr_b16 %0, %1" : "=v"(d) : "v"(addr));
  return d;
}

__device__ __forceinline__ float gelu_tanh(float x) {
  float x3 = x * x * x;
  float t  = 0.7978845608028654f * (x + 0.044715f * x3);
  float th = 1.0f - 2.0f / (__expf(2.0f * t) + 1.0f);
  return 0.5f * x * (1.0f + th);
}

// ---------------- fp32 -> bf16 cast (weights) ----------------
__global__ __launch_bounds__(256) void cast_kernel(const float* __restrict__ in,
                                                   __bf16* __restrict__ out, int n) {
  int i = (blockIdx.x * 256 + threadIdx.x) * 4;
  if (i >= n) return;
  float4 v = *(const float4*)(in + i);
  bf16x4 o;
  o[0] = (__bf16)v.x; o[1] = (__bf16)v.y; o[2] = (__bf16)v.z; o[3] = (__bf16)v.w;
  *(bf16x4*)(out + i) = o;
}

// ---------------- LayerNorm ----------------
__global__ __launch_bounds__(256) void ln_kernel(const float* __restrict__ x,
                                                 const float* __restrict__ w,
                                                 __bf16* __restrict__ out) {
  int row = blockIdx.x;
  int t = threadIdx.x;
  const float* xr = x + (size_t)row * EMB;
  float4 a = *(const float4*)(xr + t * 8);
  float4 b = *(const float4*)(xr + t * 8 + 4);
  float s  = a.x + a.y + a.z + a.w + b.x + b.y + b.z + b.w;
  float sq = a.x*a.x + a.y*a.y + a.z*a.z + a.w*a.w + b.x*b.x + b.y*b.y + b.z*b.z + b.w*b.w;
  #pragma unroll
  for (int o = 32; o > 0; o >>= 1) { s += __shfl_xor(s, o); sq += __shfl_xor(sq, o); }
  __shared__ float red[8];
  if ((t & 63) == 0) { red[t >> 6] = s; red[(t >> 6) + 4] = sq; }
  __syncthreads();
  s  = red[0] + red[1] + red[2] + red[3];
  sq = red[4] + red[5] + red[6] + red[7];
  float mu  = s * (1.0f / EMB);
  float var = sq * (1.0f / EMB) - mu * mu;
  float rs  = rsqrtf(var + 1e-5f);
  float4 w1 = *(const float4*)(w + t * 8);
  float4 w2 = *(const float4*)(w + t * 8 + 4);
  bf16x8 ov;
  ov[0] = (__bf16)((a.x - mu) * rs * w1.x);
  ov[1] = (__bf16)((a.y - mu) * rs * w1.y);
  ov[2] = (__bf16)((a.z - mu) * rs * w1.z);
  ov[3] = (__bf16)((a.w - mu) * rs * w1.w);
  ov[4] = (__bf16)((b.x - mu) * rs * w2.x);
  ov[5] = (__bf16)((b.y - mu) * rs * w2.y);
  ov[6] = (__bf16)((b.z - mu) * rs * w2.z);
  ov[7] = (__bf16)((b.w - mu) * rs * w2.w);
  *(bf16x8*)(out + (size_t)row * EMB + t * 8) = ov;
}

// ---------------- GEMM: C[M,N] = A[M,K] * B[N,K]^T ----------------
// Counted-vmcnt ring-4 pipeline: BK=32, 4 LDS slots, prefetch 3 tiles ahead,
// raw s_barrier + s_waitcnt vmcnt(8) (tail 4 -> 0), one barrier per K-tile.
// LDS chunk-swizzle: chunk ^= (row>>1)&3 (pre-swizzled global source, rule #21).
// EPI: 0 = store bf16; 2 = store bf16 gelu(acc); 4 = atomicAdd f32 (split-K)
template <int EPI>
__global__ __launch_bounds__(256) void gemm_bt(const __bf16* __restrict__ A,
                                               const __bf16* __restrict__ B,
                                               void* __restrict__ Cv,
                                               int M, int N, int K, int Ksl) {
  __shared__ __bf16 As[4][4096];   // [slot][128 rows * 32 cols]
  __shared__ __bf16 Bs[4][4096];
  const int t = threadIdx.x, w = t >> 6, l = t & 63;
  const int m0 = blockIdx.y * 128, n0 = blockIdx.x * 128;
  const int wr = w >> 1, wc = w & 1;
  const int fr = l & 15;
  const int kb = blockIdx.z * Ksl;
  const int nt = Ksl >> 5;          // K-tiles of 32 (nt >= 16 in all call sites)

  // staging: thread t covers LDS bytes [t*16, t*16+16) of a 64-row round;
  // row = t>>2, phys chunk = t&3 -> logical (source) chunk = (t&3) ^ ((t>>3)&3)
  const int srow = t >> 2;
  const int scol = ((t & 3) ^ ((t >> 3) & 3)) * 8;
  const __bf16* Asrc = A + (size_t)(m0 + srow) * K + kb + scol;
  const __bf16* Bsrc = B + (size_t)(n0 + srow) * K + kb + scol;
  const size_t rstride64 = (size_t)64 * K;

  // fragment read: logical chunk (l>>4) at row (..+fr) -> phys chunk ^ ((fr>>1)&3)
  const int pc = (((l >> 4) ^ ((l >> 1) & 3)) << 3);  // elements

  f32x4 acc[4][4] = {};

  auto stage = [&](int tile) {
    const int slot = tile & 3;
    const int koff = tile * 32;
    #pragma unroll
    for (int rd = 0; rd < 2; rd++) {
      async_copy16(&As[slot][rd * 2048 + w * 512], Asrc + rd * rstride64 + koff);
      async_copy16(&Bs[slot][rd * 2048 + w * 512], Bsrc + rd * rstride64 + koff);
    }
  };

  auto compute = [&](int tile) {
    const int slot = tile & 3;
    bf16x8 af[4], bfr[4];
    #pragma unroll
    for (int m = 0; m < 4; m++)
      af[m] = *(const bf16x8*)&As[slot][(wr * 64 + m * 16 + fr) * 32 + pc];
    #pragma unroll
    for (int n = 0; n < 4; n++)
      bfr[n] = *(const bf16x8*)&Bs[slot][(wc * 64 + n * 16 + fr) * 32 + pc];
    __builtin_amdgcn_s_setprio(1);
    #pragma unroll
    for (int m = 0; m < 4; m++)
      #pragma unroll
      for (int n = 0; n < 4; n++)
        acc[m][n] = __builtin_amdgcn_mfma_f32_16x16x32_bf16(af[m], bfr[n], acc[m][n], 0, 0, 0);
    __builtin_amdgcn_s_setprio(0);
  };

  stage(0); stage(1); stage(2);     // 12 loads in flight

  for (int tile = 0; tile < nt - 2; ++tile) {
    asm volatile("s_waitcnt vmcnt(8)" ::: "memory");   // tile's 4 loads landed
    __builtin_amdgcn_s_barrier();                       // all waves see it; reads of tile-1 done
    asm volatile("" ::: "memory");
    if (tile + 3 < nt) stage(tile + 3);                // overwrites slot of tile-1 (safe)
    compute(tile);
  }
  asm volatile("s_waitcnt vmcnt(4)" ::: "memory");
  __builtin_amdgcn_s_barrier();
  asm volatile("" ::: "memory");
  compute(nt - 2);
  asm volatile("s_waitcnt vmcnt(0)" ::: "memory");
  __builtin_amdgcn_s_barrier();
  asm volatile("" ::: "memory");
  compute(nt - 1);

  #pragma unroll
  for (int m = 0; m < 4; m++)
    #pragma unroll
    for (int n = 0; n < 4; n++)
      #pragma unroll
      for (int j = 0; j < 4; j++) {
        int orow = m0 + wr * 64 + m * 16 + (l >> 4) * 4 + j;
        int ocol = n0 + wc * 64 + n * 16 + (l & 15);
        size_t idx = (size_t)orow * N + ocol;
        float v = acc[m][n][j];
        if (EPI == 0) {
          ((__bf16*)Cv)[idx] = (__bf16)v;
        } else if (EPI == 2) {
          ((__bf16*)Cv)[idx] = (__bf16)gelu_tanh(v);
        } else {
          atomicAdd((float*)Cv + idx, v);
        }
      }
}

// ---------------- Flash attention (causal) ----------------
__global__ __launch_bounds__(256) void attn_kernel(const __bf16* __restrict__ qkv,
                                                   __bf16* __restrict__ out) {
  __shared__ __bf16 Kt[2][64 * 128];
  __shared__ __bf16 Vt[2][64 * 128];
  __shared__ __bf16 Pb[4][16 * 64];

  const int bid = blockIdx.x;
  const int h = bid & 15;
  const int idx = bid >> 4;
  const int qb = (idx < 16) ? idx : 47 - idx;

  const int t = threadIdx.x, w = t >> 6, l = t & 63;
  const int g = l >> 4, fr = l & 15;
  const int fkb = g * 8;
  const int q0 = qb * 64 + w * 16;
  const float scale = 0.08838834764831845f; // 1/sqrt(128)

  const int krow = w * 4 + g;
  const int kchunk = fr ^ (krow & 7);
  const int vkey = (l >> 1) & 3;
  const int vd0  = (l >> 3) * 16 + (l & 1) * 8;

  const size_t row3E = (size_t)(3 * EMB);
  const __bf16* Kg = qkv + EMB + h * HD;
  const __bf16* Vg = qkv + 2 * EMB + h * HD;

  bf16x8 qf[4];
  #pragma unroll
  for (int kc = 0; kc < 4; kc++)
    qf[kc] = *(const bf16x8*)&qkv[(size_t)(q0 + fr) * row3E + h * HD + kc * 32 + fkb];

  f32x4 o[8] = {};
  float mrun[4] = {-1e30f, -1e30f, -1e30f, -1e30f};
  float lsum[4] = {0.f, 0.f, 0.f, 0.f};

  const unsigned vtrb[2] = { lds_addr(&Vt[0][0]) + g * 2048 + fr * 8,
                             lds_addr(&Vt[1][0]) + g * 2048 + fr * 8 };

  auto stage = [&](int buf, int it) {
    const int t0 = it * 64;
    #pragma unroll
    for (int r = 0; r < 4; r++) {
      async_copy16(&Kt[buf][r * 2048 + w * 512],
                   Kg + (size_t)(t0 + r * 16 + krow) * row3E + kchunk * 8);
      async_copy16(&Vt[buf][(r * 4 + w) * 512],
                   Vg + (size_t)(t0 + r * 16 + w * 4 + vkey) * row3E + vd0);
    }
  };

  const int nt = qb + 1;
  stage(0, 0);
  int cur = 0;

  for (int it = 0; it < nt; it++) {
    __syncthreads();
    if (it + 1 < nt) stage(cur ^ 1, it + 1);
    const int t0 = it * 64;

    f32x4 s[4] = {};
    #pragma unroll
    for (int n = 0; n < 4; n++)
      #pragma unroll
      for (int kc = 0; kc < 4; kc++) {
        bf16x8 kf = *(const bf16x8*)&Kt[cur][(n * 16 + fr) * 128 +
                                            (((kc * 4 + g) ^ (fr & 7)) << 3)];
        s[n] = __builtin_amdgcn_mfma_f32_16x16x32_bf16(qf[kc], kf, s[n], 0, 0, 0);
      }
    #pragma unroll
    for (int n = 0; n < 4; n++)
      #pragma unroll
      for (int j = 0; j < 4; j++) {
        int tcol = t0 + n * 16 + fr;
        int qrow = q0 + g * 4 + j;
        float v = s[n][j] * scale;
        s[n][j] = (tcol > qrow) ? -1e30f : v;
      }
    float pm[4];
    #pragma unroll
    for (int j = 0; j < 4; j++) {
      pm[j] = fmaxf(fmaxf(s[0][j], s[1][j]), fmaxf(s[2][j], s[3][j]));
      #pragma unroll
      for (int off = 1; off < 16; off <<= 1) pm[j] = fmaxf(pm[j], __shfl_xor(pm[j], off));
    }
    float factor[4];
    #pragma unroll
    for (int j = 0; j < 4; j++) {
      float mn = fmaxf(mrun[j], pm[j]);
      factor[j] = __expf(mrun[j] - mn);
      mrun[j] = mn;
    }
    float rs[4] = {0.f, 0.f, 0.f, 0.f};
    #pragma unroll
    for (int n = 0; n < 4; n++)
      #pragma unroll
      for (int j = 0; j < 4; j++) {
        float p = __expf(s[n][j] - mrun[j]);
        s[n][j] = p;
        rs[j] += p;
      }
    #pragma unroll
    for (int j = 0; j < 4; j++) {
      #pragma unroll
      for (int off = 1; off < 16; off <<= 1) rs[j] += __shfl_xor(rs[j], off);
      lsum[j] = lsum[j] * factor[j] + rs[j];
    }
    #pragma unroll
    for (int b = 0; b < 8; b++)
      #pragma unroll
      for (int j = 0; j < 4; j++) o[b][j] *= factor[j];

    #pragma unroll
    for (int n = 0; n < 4; n++)
      #pragma unroll
      for (int j = 0; j < 4; j++) {
        int q   = g * 4 + j;
        int key = n * 16 + fr;
        int cs  = (key >> 3) ^ (q & 7);
        Pb[w][q * 64 + cs * 8 + (key & 7)] = (__bf16)s[n][j];
      }

    bf16x8 pf[2];
    #pragma unroll
    for (int kc = 0; kc < 2; kc++)
      pf[kc] = *(const bf16x8*)&Pb[w][fr * 64 + (((kc * 4 + g) ^ (fr & 7)) << 3)];

    const unsigned vtr = vtrb[cur];
    #pragma unroll
    for (int b = 0; b < 8; b++) {
      s16x4 t00 = tr16(vtr + b * 128);
      s16x4 t01 = tr16(vtr + b * 128 + 1024);
      s16x4 t10 = tr16(vtr + b * 128 + 8192);
      s16x4 t11 = tr16(vtr + b * 128 + 8192 + 1024);
      asm volatile("s_waitcnt lgkmcnt(0)");
      __builtin_amdgcn_sched_barrier(0);
      union { s16x4 hh[2]; bf16x8 v; } u0, u1;
      u0.hh[0] = t00; u0.hh[1] = t01;
      u1.hh[0] = t10; u1.hh[1] = t11;
      o[b] = __builtin_amdgcn_mfma_f32_16x16x32_bf16(pf[0], u0.v, o[b], 0, 0, 0);
      o[b] = __builtin_amdgcn_mfma_f32_16x16x32_bf16(pf[1], u1.v, o[b], 0, 0, 0);
    }
    cur ^= 1;
  }

  float rcp[4];
  #pragma unroll
  for (int j = 0; j < 4; j++) rcp[j] = 1.0f / lsum[j];
  #pragma unroll
  for (int b = 0; b < 8; b++)
    #pragma unroll
    for (int j = 0; j < 4; j++) {
      int qrow = q0 + g * 4 + j;
      out[(size_t)qrow * EMB + h * HD + b * 16 + fr] = (__bf16)(o[b][j] * rcp[j]);
    }
}

// ---------------- launch ----------------
extern "C" void kernel_launch(void* const* d_in, const int* in_sizes, int n_in,
                              void* d_out, int out_size, void* d_ws, size_t ws_size,
                              hipStream_t stream) {
  const float* x     = (const float*)d_in[0];
  const float* ln1w  = (const float*)d_in[1];
  const float* ln2w  = (const float*)d_in[2];
  const float* wattn = (const float*)d_in[3];
  const float* wproja= (const float*)d_in[4];
  const float* wfc   = (const float*)d_in[5];
  const float* wprojf= (const float*)d_in[6];
  float* out = (float*)d_out;
  char* ws = (char*)d_ws;

  __bf16* wattn_b  = (__bf16*)(ws);                 // 3E*E
  __bf16* wproja_b = (__bf16*)(ws + 25165824);      // E*E
  __bf16* wfc_b    = (__bf16*)(ws + 33554432);      // 4E*E
  __bf16* wprojf_b = (__bf16*)(ws + 67108864);      // E*4E
  __bf16* h_b      = (__bf16*)(ws + 100663296);     // S*E
  __bf16* qkv_b    = (__bf16*)(ws + 109051904);     // S*3E
  __bf16* attn_b   = (__bf16*)(ws + 134217728);     // S*E
  __bf16* f1_b     = (__bf16*)(ws + 142606336);     // S*4E

  cast_kernel<<<12288, 256, 0, stream>>>(wattn,  wattn_b,  12582912);
  cast_kernel<<<4096,  256, 0, stream>>>(wproja, wproja_b, 4194304);
  cast_kernel<<<16384, 256, 0, stream>>>(wfc,    wfc_b,    16777216);
  cast_kernel<<<16384, 256, 0, stream>>>(wprojf, wprojf_b, 16777216);

  ln_kernel<<<S_LEN, 256, 0, stream>>>(x, ln1w, h_b);
  // QKV: [2048, 6144]
  gemm_bt<0><<<dim3(48, 16), 256, 0, stream>>>(h_b, wattn_b, qkv_b, S_LEN, 3 * EMB, EMB, EMB);
  attn_kernel<<<dim3(512), 256, 0, stream>>>(qkv_b, attn_b);
  // seed out with residual x, then attn proj as split-K x4 atomicAdd
  hipMemcpyAsync(out, x, (size_t)S_LEN * EMB * sizeof(float), hipMemcpyDeviceToDevice, stream);
  gemm_bt<4><<<dim3(16, 16, 4), 256, 0, stream>>>(attn_b, wproja_b, out, S_LEN, EMB, EMB, EMB / 4);
  ln_kernel<<<S_LEN, 256, 0, stream>>>(out, ln2w, h_b);
  // FC + GELU: [2048, 8192]
  gemm_bt<2><<<dim3(64, 16), 256, 0, stream>>>(h_b, wfc_b, f1_b, S_LEN, 4 * EMB, EMB, EMB);
  // FFN proj, split-K x4 atomicAdd into out
  gemm_bt<4><<<dim3(16, 16, 4), 256, 0, stream>>>(f1_b, wprojf_b, out, S_LEN, EMB, 4 * EMB, EMB);
}

// Round 7
// 468.844 us; speedup vs baseline: 1.1411x; 1.1411x over previous
//
#include <hip/hip_runtime.h>
#include <hip/hip_bf16.h>

// S=2048, E=2048, H=16, D=128
#define S_LEN 2048
#define EMB   2048
#define NH    16
#define HD    128

typedef __bf16 bf16x8 __attribute__((ext_vector_type(8)));
typedef __bf16 bf16x4 __attribute__((ext_vector_type(4)));
typedef float  f32x4  __attribute__((ext_vector_type(4)));
typedef short  s16x4  __attribute__((ext_vector_type(4)));

__device__ __forceinline__ void async_copy16(void* lds, const void* g) {
  __builtin_amdgcn_global_load_lds((__attribute__((address_space(1))) void*)(void*)g,
                                   (__attribute__((address_space(3))) void*)lds, 16, 0, 0);
}

__device__ __forceinline__ unsigned lds_addr(const void* p) {
  return (unsigned)(uintptr_t)(const __attribute__((address_space(3))) char*)p;
}

__device__ __forceinline__ s16x4 tr16(unsigned addr) {
  s16x4 d;
  asm volatile("ds_read_b64_tr_b16 %0, %1" : "=v"(d) : "v"(addr));
  return d;
}

__device__ __forceinline__ float gelu_tanh(float x) {
  float x3 = x * x * x;
  float t  = 0.7978845608028654f * (x + 0.044715f * x3);
  float th = 1.0f - 2.0f / (__expf(2.0f * t) + 1.0f);
  return 0.5f * x * (1.0f + th);
}

// ---------------- fp32 -> bf16 cast (weights) ----------------
__global__ __launch_bounds__(256) void cast_kernel(const float* __restrict__ in,
                                                   __bf16* __restrict__ out, int n) {
  int i = (blockIdx.x * 256 + threadIdx.x) * 4;
  if (i >= n) return;
  float4 v = *(const float4*)(in + i);
  bf16x4 o;
  o[0] = (__bf16)v.x; o[1] = (__bf16)v.y; o[2] = (__bf16)v.z; o[3] = (__bf16)v.w;
  *(bf16x4*)(out + i) = o;
}

// ---------------- LayerNorm ----------------
__global__ __launch_bounds__(256) void ln_kernel(const float* __restrict__ x,
                                                 const float* __restrict__ w,
                                                 __bf16* __restrict__ out) {
  int row = blockIdx.x;
  int t = threadIdx.x;
  const float* xr = x + (size_t)row * EMB;
  float4 a = *(const float4*)(xr + t * 8);
  float4 b = *(const float4*)(xr + t * 8 + 4);
  float s  = a.x + a.y + a.z + a.w + b.x + b.y + b.z + b.w;
  float sq = a.x*a.x + a.y*a.y + a.z*a.z + a.w*a.w + b.x*b.x + b.y*b.y + b.z*b.z + b.w*b.w;
  #pragma unroll
  for (int o = 32; o > 0; o >>= 1) { s += __shfl_xor(s, o); sq += __shfl_xor(sq, o); }
  __shared__ float red[8];
  if ((t & 63) == 0) { red[t >> 6] = s; red[(t >> 6) + 4] = sq; }
  __syncthreads();
  s  = red[0] + red[1] + red[2] + red[3];
  sq = red[4] + red[5] + red[6] + red[7];
  float mu  = s * (1.0f / EMB);
  float var = sq * (1.0f / EMB) - mu * mu;
  float rs  = rsqrtf(var + 1e-5f);
  float4 w1 = *(const float4*)(w + t * 8);
  float4 w2 = *(const float4*)(w + t * 8 + 4);
  bf16x8 ov;
  ov[0] = (__bf16)((a.x - mu) * rs * w1.x);
  ov[1] = (__bf16)((a.y - mu) * rs * w1.y);
  ov[2] = (__bf16)((a.z - mu) * rs * w1.z);
  ov[3] = (__bf16)((a.w - mu) * rs * w1.w);
  ov[4] = (__bf16)((b.x - mu) * rs * w2.x);
  ov[5] = (__bf16)((b.y - mu) * rs * w2.y);
  ov[6] = (__bf16)((b.z - mu) * rs * w2.z);
  ov[7] = (__bf16)((b.w - mu) * rs * w2.w);
  *(bf16x8*)(out + (size_t)row * EMB + t * 8) = ov;
}

// ---------------- 256x256 8-phase GEMM: C[M,N] = A[M,K]*B[N,K]^T ----------------
// 512 threads = 8 waves (2 M x 4 N). BK=64, K-tile = 4 units {A-kh0, B-kh0, A-kh1, B-kh1},
// each unit 256x32 bf16 = 16 KB staged by 2 global_load_lds/thread. LDS dbuf = 128 KB.
// Per K-tile: 4 phases, counted vmcnt(4) twice per tile (never 0 until tail).
// Swizzle: 16B granule ^ (row&3) within each 64B row (both-sides involution).
// EPI: 0 = store bf16; 2 = store bf16 gelu(acc); 4 = atomicAdd f32 (split-K)
#define GPHASE(KH, MG, LOADB, STAGE_CALL, VMWAIT)                                           \
  {                                                                                         \
    if (LOADB) {                                                                            \
      _Pragma("unroll")                                                                     \
      for (int n = 0; n < 4; n++) {                                                         \
        int row = wc * 64 + n * 16 + fr;                                                    \
        b[n] = *(const bf16x8*)&Bs[((p * 2 + (KH)) * 256 + row) * 32 + ((g ^ (fr & 3)) << 3)]; \
      }                                                                                     \
    }                                                                                       \
    _Pragma("unroll")                                                                       \
    for (int m = 0; m < 4; m++) {                                                           \
      int row = wr * 128 + ((MG) * 4 + m) * 16 + fr;                                        \
      a[m] = *(const bf16x8*)&As[((p * 2 + (KH)) * 256 + row) * 32 + ((g ^ (fr & 3)) << 3)];   \
    }                                                                                       \
    STAGE_CALL;                                                                             \
    __builtin_amdgcn_sched_barrier(0);                                                      \
    __builtin_amdgcn_s_setprio(1);                                                          \
    _Pragma("unroll")                                                                       \
    for (int m = 0; m < 4; m++)                                                             \
      _Pragma("unroll")                                                                     \
      for (int n = 0; n < 4; n++)                                                           \
        acc[(MG) * 4 + m][n] =                                                              \
            __builtin_amdgcn_mfma_f32_16x16x32_bf16(a[m], b[n], acc[(MG) * 4 + m][n], 0, 0, 0); \
    __builtin_amdgcn_s_setprio(0);                                                          \
    VMWAIT;                                                                                 \
    __builtin_amdgcn_s_barrier();                                                           \
  }

template <int EPI>
__global__ __launch_bounds__(512, 2) void gemm256(const __bf16* __restrict__ A,
                                                  const __bf16* __restrict__ B,
                                                  void* __restrict__ Cv,
                                                  int M, int N, int K, int Ksl, int NN) {
  __shared__ __bf16 As[2 * 2 * 256 * 32];   // [buf][kh][row 256][col 32] = 64 KB
  __shared__ __bf16 Bs[2 * 2 * 256 * 32];

  const int t = threadIdx.x, w = t >> 6, l = t & 63;
  const int fr = l & 15, g = l >> 4;
  const int wr = w >> 2, wc = w & 3;

  // XCD-bijective block swizzle (nwg % 8 == 0 at all call sites)
  const int nwg = gridDim.x;
  const int wg = (blockIdx.x & 7) * (nwg >> 3) + (blockIdx.x >> 3);
  const int NMN = (M >> 8) * NN;
  const int z = wg / NMN, rr = wg - z * NMN;
  const int my = rr / NN, nx = rr - my * NN;
  const int m0 = my * 256, n0 = nx * 256;
  const int kb = z * Ksl;
  const int NT = Ksl >> 6;

  // staging coordinates: thread t covers row (t>>2) (+128 for 2nd gload), granule t&3
  const int srow = t >> 2;
  const int schunk = (t & 3) ^ ((t >> 2) & 3);           // pre-swizzled source granule
  const __bf16* Abase = A + (size_t)(m0 + srow) * K + kb + schunk * 8;
  const __bf16* Bbase = B + (size_t)(n0 + srow) * K + kb + schunk * 8;
  const size_t K128 = (size_t)128 * K;
  __bf16* AsT = &As[t * 8];
  __bf16* BsT = &Bs[t * 8];

  auto stageA = [&](int pp, int kt2, int kh) {
    const __bf16* src = Abase + kt2 * 64 + kh * 32;
    __bf16* dst = AsT + (pp * 2 + kh) * 8192;
    async_copy16(dst, src);
    async_copy16(dst + 4096, src + K128);
  };
  auto stageB = [&](int pp, int kt2, int kh) {
    const __bf16* src = Bbase + kt2 * 64 + kh * 32;
    __bf16* dst = BsT + (pp * 2 + kh) * 8192;
    async_copy16(dst, src);
    async_copy16(dst + 4096, src + K128);
  };

  f32x4 acc[8][4] = {};

  // prologue: stage all 4 units of tile 0 into buf 0
  stageA(0, 0, 0); stageB(0, 0, 0); stageA(0, 0, 1); stageB(0, 0, 1);
  asm volatile("s_waitcnt vmcnt(4)" ::: "memory");   // units 0,1 landed
  __builtin_amdgcn_s_barrier();

  for (int kt = 0; kt < NT; ++kt) {
    const int p = kt & 1, pn = p ^ 1;
    const bool pref = (kt + 1 < NT);
    bf16x8 a[4], b[4];
    // ph0: B(kh0) + A(kh0, mg0); stage A-kh0 of t+1
    GPHASE(0, 0, 1, if (pref) stageA(pn, kt + 1, 0), (void)0);
    // ph1: A(kh0, mg1); stage B-kh0 of t+1; vmcnt ensures units 2,3 of THIS tile landed
    GPHASE(0, 1, 0, if (pref) stageB(pn, kt + 1, 0),
           if (pref) { asm volatile("s_waitcnt vmcnt(4)" ::: "memory"); }
           else      { asm volatile("s_waitcnt vmcnt(0)" ::: "memory"); });
    // ph2: B(kh1) + A(kh1, mg0); stage A-kh1 of t+1
    GPHASE(1, 0, 1, if (pref) stageA(pn, kt + 1, 1), (void)0);
    // ph3: A(kh1, mg1); stage B-kh1 of t+1; vmcnt ensures units 0,1 of t+1 landed
    GPHASE(1, 1, 0, if (pref) stageB(pn, kt + 1, 1),
           if (pref) { asm volatile("s_waitcnt vmcnt(4)" ::: "memory"); });
  }

  #pragma unroll
  for (int m = 0; m < 8; m++)
    #pragma unroll
    for (int n = 0; n < 4; n++)
      #pragma unroll
      for (int j = 0; j < 4; j++) {
        int orow = m0 + wr * 128 + m * 16 + g * 4 + j;
        int ocol = n0 + wc * 64 + n * 16 + fr;
        size_t idx = (size_t)orow * N + ocol;
        float v = acc[m][n][j];
        if (EPI == 0) {
          ((__bf16*)Cv)[idx] = (__bf16)v;
        } else if (EPI == 2) {
          ((__bf16*)Cv)[idx] = (__bf16)gelu_tanh(v);
        } else {
          atomicAdd((float*)Cv + idx, v);
        }
      }
}

// ---------------- Flash attention (causal) ----------------
__global__ __launch_bounds__(256) void attn_kernel(const __bf16* __restrict__ qkv,
                                                   __bf16* __restrict__ out) {
  __shared__ __bf16 Kt[2][64 * 128];
  __shared__ __bf16 Vt[2][64 * 128];
  __shared__ __bf16 Pb[4][16 * 64];

  const int bid = blockIdx.x;
  const int h = bid & 15;
  const int idx = bid >> 4;
  const int qb = (idx < 16) ? idx : 47 - idx;

  const int t = threadIdx.x, w = t >> 6, l = t & 63;
  const int g = l >> 4, fr = l & 15;
  const int fkb = g * 8;
  const int q0 = qb * 64 + w * 16;
  const float scale = 0.08838834764831845f; // 1/sqrt(128)

  const int krow = w * 4 + g;
  const int kchunk = fr ^ (krow & 7);
  const int vkey = (l >> 1) & 3;
  const int vd0  = (l >> 3) * 16 + (l & 1) * 8;

  const size_t row3E = (size_t)(3 * EMB);
  const __bf16* Kg = qkv + EMB + h * HD;
  const __bf16* Vg = qkv + 2 * EMB + h * HD;

  bf16x8 qf[4];
  #pragma unroll
  for (int kc = 0; kc < 4; kc++)
    qf[kc] = *(const bf16x8*)&qkv[(size_t)(q0 + fr) * row3E + h * HD + kc * 32 + fkb];

  f32x4 o[8] = {};
  float mrun[4] = {-1e30f, -1e30f, -1e30f, -1e30f};
  float lsum[4] = {0.f, 0.f, 0.f, 0.f};

  const unsigned vtrb[2] = { lds_addr(&Vt[0][0]) + g * 2048 + fr * 8,
                             lds_addr(&Vt[1][0]) + g * 2048 + fr * 8 };

  auto stage = [&](int buf, int it) {
    const int t0 = it * 64;
    #pragma unroll
    for (int r = 0; r < 4; r++) {
      async_copy16(&Kt[buf][r * 2048 + w * 512],
                   Kg + (size_t)(t0 + r * 16 + krow) * row3E + kchunk * 8);
      async_copy16(&Vt[buf][(r * 4 + w) * 512],
                   Vg + (size_t)(t0 + r * 16 + w * 4 + vkey) * row3E + vd0);
    }
  };

  const int nt = qb + 1;
  stage(0, 0);
  int cur = 0;

  for (int it = 0; it < nt; it++) {
    __syncthreads();
    if (it + 1 < nt) stage(cur ^ 1, it + 1);
    const int t0 = it * 64;

    f32x4 s[4] = {};
    #pragma unroll
    for (int n = 0; n < 4; n++)
      #pragma unroll
      for (int kc = 0; kc < 4; kc++) {
        bf16x8 kf = *(const bf16x8*)&Kt[cur][(n * 16 + fr) * 128 +
                                            (((kc * 4 + g) ^ (fr & 7)) << 3)];
        s[n] = __builtin_amdgcn_mfma_f32_16x16x32_bf16(qf[kc], kf, s[n], 0, 0, 0);
      }
    #pragma unroll
    for (int n = 0; n < 4; n++)
      #pragma unroll
      for (int j = 0; j < 4; j++) {
        int tcol = t0 + n * 16 + fr;
        int qrow = q0 + g * 4 + j;
        float v = s[n][j] * scale;
        s[n][j] = (tcol > qrow) ? -1e30f : v;
      }
    float pm[4];
    #pragma unroll
    for (int j = 0; j < 4; j++) {
      pm[j] = fmaxf(fmaxf(s[0][j], s[1][j]), fmaxf(s[2][j], s[3][j]));
      #pragma unroll
      for (int off = 1; off < 16; off <<= 1) pm[j] = fmaxf(pm[j], __shfl_xor(pm[j], off));
    }
    float factor[4];
    #pragma unroll
    for (int j = 0; j < 4; j++) {
      float mn = fmaxf(mrun[j], pm[j]);
      factor[j] = __expf(mrun[j] - mn);
      mrun[j] = mn;
    }
    float rs[4] = {0.f, 0.f, 0.f, 0.f};
    #pragma unroll
    for (int n = 0; n < 4; n++)
      #pragma unroll
      for (int j = 0; j < 4; j++) {
        float p = __expf(s[n][j] - mrun[j]);
        s[n][j] = p;
        rs[j] += p;
      }
    #pragma unroll
    for (int j = 0; j < 4; j++) {
      #pragma unroll
      for (int off = 1; off < 16; off <<= 1) rs[j] += __shfl_xor(rs[j], off);
      lsum[j] = lsum[j] * factor[j] + rs[j];
    }
    #pragma unroll
    for (int b = 0; b < 8; b++)
      #pragma unroll
      for (int j = 0; j < 4; j++) o[b][j] *= factor[j];

    #pragma unroll
    for (int n = 0; n < 4; n++)
      #pragma unroll
      for (int j = 0; j < 4; j++) {
        int q   = g * 4 + j;
        int key = n * 16 + fr;
        int cs  = (key >> 3) ^ (q & 7);
        Pb[w][q * 64 + cs * 8 + (key & 7)] = (__bf16)s[n][j];
      }

    bf16x8 pf[2];
    #pragma unroll
    for (int kc = 0; kc < 2; kc++)
      pf[kc] = *(const bf16x8*)&Pb[w][fr * 64 + (((kc * 4 + g) ^ (fr & 7)) << 3)];

    const unsigned vtr = vtrb[cur];
    #pragma unroll
    for (int b = 0; b < 8; b++) {
      s16x4 t00 = tr16(vtr + b * 128);
      s16x4 t01 = tr16(vtr + b * 128 + 1024);
      s16x4 t10 = tr16(vtr + b * 128 + 8192);
      s16x4 t11 = tr16(vtr + b * 128 + 8192 + 1024);
      asm volatile("s_waitcnt lgkmcnt(0)");
      __builtin_amdgcn_sched_barrier(0);
      union { s16x4 hh[2]; bf16x8 v; } u0, u1;
      u0.hh[0] = t00; u0.hh[1] = t01;
      u1.hh[0] = t10; u1.hh[1] = t11;
      o[b] = __builtin_amdgcn_mfma_f32_16x16x32_bf16(pf[0], u0.v, o[b], 0, 0, 0);
      o[b] = __builtin_amdgcn_mfma_f32_16x16x32_bf16(pf[1], u1.v, o[b], 0, 0, 0);
    }
    cur ^= 1;
  }

  float rcp[4];
  #pragma unroll
  for (int j = 0; j < 4; j++) rcp[j] = 1.0f / lsum[j];
  #pragma unroll
  for (int b = 0; b < 8; b++)
    #pragma unroll
    for (int j = 0; j < 4; j++) {
      int qrow = q0 + g * 4 + j;
      out[(size_t)qrow * EMB + h * HD + b * 16 + fr] = (__bf16)(o[b][j] * rcp[j]);
    }
}

// ---------------- launch ----------------
extern "C" void kernel_launch(void* const* d_in, const int* in_sizes, int n_in,
                              void* d_out, int out_size, void* d_ws, size_t ws_size,
                              hipStream_t stream) {
  const float* x     = (const float*)d_in[0];
  const float* ln1w  = (const float*)d_in[1];
  const float* ln2w  = (const float*)d_in[2];
  const float* wattn = (const float*)d_in[3];
  const float* wproja= (const float*)d_in[4];
  const float* wfc   = (const float*)d_in[5];
  const float* wprojf= (const float*)d_in[6];
  float* out = (float*)d_out;
  char* ws = (char*)d_ws;

  __bf16* wattn_b  = (__bf16*)(ws);                 // 3E*E
  __bf16* wproja_b = (__bf16*)(ws + 25165824);      // E*E
  __bf16* wfc_b    = (__bf16*)(ws + 33554432);      // 4E*E
  __bf16* wprojf_b = (__bf16*)(ws + 67108864);      // E*4E
  __bf16* h_b      = (__bf16*)(ws + 100663296);     // S*E
  __bf16* qkv_b    = (__bf16*)(ws + 109051904);     // S*3E
  __bf16* attn_b   = (__bf16*)(ws + 134217728);     // S*E
  __bf16* f1_b     = (__bf16*)(ws + 142606336);     // S*4E

  cast_kernel<<<12288, 256, 0, stream>>>(wattn,  wattn_b,  12582912);
  cast_kernel<<<4096,  256, 0, stream>>>(wproja, wproja_b, 4194304);
  cast_kernel<<<16384, 256, 0, stream>>>(wfc,    wfc_b,    16777216);
  cast_kernel<<<16384, 256, 0, stream>>>(wprojf, wprojf_b, 16777216);

  ln_kernel<<<S_LEN, 256, 0, stream>>>(x, ln1w, h_b);
  // QKV: [2048, 6144], NN=24, 192 blocks
  gemm256<0><<<192, 512, 0, stream>>>(h_b, wattn_b, qkv_b, S_LEN, 3 * EMB, EMB, EMB, 24);
  attn_kernel<<<dim3(512), 256, 0, stream>>>(qkv_b, attn_b);
  // seed out with residual x, then attn proj split-K x4 atomicAdd (8x8x4 = 256 blocks)
  (void)hipMemcpyAsync(out, x, (size_t)S_LEN * EMB * sizeof(float), hipMemcpyDeviceToDevice, stream);
  gemm256<4><<<256, 512, 0, stream>>>(attn_b, wproja_b, out, S_LEN, EMB, EMB, EMB / 4, 8);
  ln_kernel<<<S_LEN, 256, 0, stream>>>(out, ln2w, h_b);
  // FC + GELU: [2048, 8192], NN=32, 256 blocks
  gemm256<2><<<256, 512, 0, stream>>>(h_b, wfc_b, f1_b, S_LEN, 4 * EMB, EMB, EMB, 32);
  // FFN proj: split-K x4 atomicAdd, Ksl=2048
  gemm256<4><<<256, 512, 0, stream>>>(f1_b, wprojf_b, out, S_LEN, EMB, 4 * EMB, 2048, 8);
}